// Round 4
// baseline (220.121 us; speedup 1.0000x reference)
//
#include <hip/hip_runtime.h>
#include <hip/hip_bf16.h>

#define BB 2
#define SS 4096
#define DM 768
#define NH 12
#define OUTC 512
#define QSCALE 0.125f

__device__ __forceinline__ float wave_sum64(float v) {
#pragma unroll
  for (int o = 32; o > 0; o >>= 1) v += __shfl_xor(v, o, 64);
  return v;
}

// kQ: partial qg: qpart[b,h,js][d] = sum_{j in 96-slice} x[b,0,j] * wqg[j, h*64+d]
__global__ __launch_bounds__(256) void kQ(const float* __restrict__ x,
    const float* __restrict__ wqg, float* __restrict__ qpart) {
  int h = blockIdx.x, b = blockIdx.y, js = blockIdx.z, t = threadIdx.x;
  __shared__ float x0[96];
  __shared__ float red[4][64];
  if (t < 96) x0[t] = x[(size_t)b*SS*DM + js*96 + t];
  __syncthreads();
  int d = t & 63, g = t >> 6;
  float acc = 0.f;
  for (int k = 0; k < 24; ++k) {
    int j = js*96 + g*24 + k;
    acc += x0[g*24 + k] * wqg[(size_t)j*DM + h*64 + d];
  }
  red[g][d] = acc;
  __syncthreads();
  if (t < 64)
    qpart[(((size_t)b*NH + h)*8 + js)*64 + t] =
        red[0][t] + red[1][t] + red[2][t] + red[3][t];
}

// kQf: qg0[b,h,d] = (sum_js qpart + bqg)*QSCALE; qb[b,h] = qg0 . bkg[h-slice]; zero l.
__global__ __launch_bounds__(64) void kQf(const float* __restrict__ qpart,
    const float* __restrict__ bqg, const float* __restrict__ bkg,
    float* __restrict__ qg_ws, float* __restrict__ qb_ws, float* __restrict__ l_ws) {
  int h = blockIdx.x, b = blockIdx.y, t = threadIdx.x;
  float s = 0.f;
#pragma unroll
  for (int js = 0; js < 8; ++js)
    s += qpart[(((size_t)b*NH + h)*8 + js)*64 + t];
  float qg = (s + bqg[h*64 + t]) * QSCALE;
  qg_ws[((size_t)b*NH + h)*64 + t] = qg;
  float qb = wave_sum64(qg * bkg[h*64 + t]);
  if (t == 0) { qb_ws[b*NH + h] = qb; l_ws[b*NH + h] = 0.f; }
}

// kA': qw[b,h,j] = qg0[b,h,:] . wkg[j, h*64:+64]
__global__ __launch_bounds__(192) void kAp(const float* __restrict__ qg_ws,
    const float* __restrict__ wkg, float* __restrict__ qw_ws) {
  int h = blockIdx.x, b = blockIdx.y, js = blockIdx.z, t = threadIdx.x;
  __shared__ float4 qg4[16];
  if (t < 16) qg4[t] = ((const float4*)qg_ws)[((size_t)b*NH + h)*16 + t];
  __syncthreads();
  int j = js*192 + t;
  const float4* wr = (const float4*)wkg + (size_t)j*192 + h*16;
  float acc = 0.f;
#pragma unroll
  for (int q = 0; q < 16; ++q) {
    float4 wv = wr[q], qv = qg4[q];
    acc += wv.x*qv.x + wv.y*qv.y + wv.z*qv.z + wv.w*qv.w;
  }
  qw_ws[((size_t)b*NH + h)*DM + j] = acc;
}

// kB: fused scores + exp + l atomics + weighted x row-sum partial writes.
// Grid (nchunk, BB), 256 threads, CS rows per chunk.
template<int CS>
__global__ __launch_bounds__(256) void kB(const float* __restrict__ x,
    const float* __restrict__ qw_ws, const float* __restrict__ qb_ws,
    float* __restrict__ l_ws, float* __restrict__ part, int nchunk) {
  int chunk = blockIdx.x, b = blockIdx.y;
  int t = threadIdx.x, lane = t & 63, w = t >> 6;
  __shared__ alignas(16) float qw[NH*DM];   // 36 KB
  __shared__ float qb[NH];
  __shared__ alignas(16) float pl[CS*NH];
  for (int i = t; i < NH*DM; i += 256) qw[i] = qw_ws[(size_t)b*NH*DM + i];
  if (t < NH) qb[t] = qb_ws[b*NH + t];
  __syncthreads();
  const size_t xbase = ((size_t)b*SS + (size_t)chunk*CS) * DM;
  const float4* x4 = (const float4*)(x + xbase);
  const float4* qw4 = (const float4*)qw;
  float lacc = 0.f;

#pragma unroll
  for (int batch = 0; batch < CS/16; ++batch) {
    int sl = w*(CS/4) + batch*4;
    float acc[4][NH];
#pragma unroll
    for (int si = 0; si < 4; ++si)
#pragma unroll
      for (int hh = 0; hh < NH; ++hh) acc[si][hh] = 0.f;
#pragma unroll
    for (int k = 0; k < 3; ++k) {
      int jq = k*64 + lane;
      float4 xf[4];
#pragma unroll
      for (int si = 0; si < 4; ++si)
        xf[si] = x4[(size_t)(sl + si)*192 + jq];
#pragma unroll
      for (int hh = 0; hh < NH; ++hh) {
        float4 qv = qw4[hh*192 + jq];
#pragma unroll
        for (int si = 0; si < 4; ++si)
          acc[si][hh] += xf[si].x*qv.x + xf[si].y*qv.y + xf[si].z*qv.z + xf[si].w*qv.w;
      }
    }
    float preg = 0.f;
#pragma unroll
    for (int si = 0; si < 4; ++si)
#pragma unroll
      for (int hh = 0; hh < NH; ++hh) {
        float r = wave_sum64(acc[si][hh]);
        float pp = __expf(r + qb[hh]);
        if (lane == hh) lacc += pp;
        if (lane == si*NH + hh) preg = pp;
      }
    if (lane < 4*NH) pl[(sl + lane/NH)*NH + (lane % NH)] = preg;
  }
  if (lane < NH) atomicAdd(&l_ws[b*NH + lane], lacc);
  __syncthreads();

  // phase 2: partial[h][j] = sum_{s in chunk} p[s,h] * x[s,j], written (no atomics)
  float a2[NH][3];
#pragma unroll
  for (int hh = 0; hh < NH; ++hh)
#pragma unroll
    for (int i = 0; i < 3; ++i) a2[hh][i] = 0.f;
  for (int s = 0; s < CS; ++s) {
    float4 p0 = *(const float4*)(&pl[s*NH + 0]);
    float4 p1 = *(const float4*)(&pl[s*NH + 4]);
    float4 p2 = *(const float4*)(&pl[s*NH + 8]);
    float pv[NH] = {p0.x,p0.y,p0.z,p0.w, p1.x,p1.y,p1.z,p1.w, p2.x,p2.y,p2.z,p2.w};
    float xv[3];
#pragma unroll
    for (int i = 0; i < 3; ++i)
      xv[i] = x[xbase + (size_t)s*DM + t + 256*i];
#pragma unroll
    for (int hh = 0; hh < NH; ++hh)
#pragma unroll
      for (int i = 0; i < 3; ++i) a2[hh][i] += pv[hh]*xv[i];
  }
  float* dst = part + ((size_t)(b*nchunk + chunk)*NH)*DM;
#pragma unroll
  for (int hh = 0; hh < NH; ++hh)
#pragma unroll
    for (int i = 0; i < 3; ++i) dst[hh*DM + t + 256*i] = a2[hh][i];
}

// kR: xw_n[b,h,j] = (sum_c part[b,c,h,j]) / l[b,h]; also zero the 4608-float
// accumulator region (out0acc, attnraw, pooledraw).
__global__ __launch_bounds__(192) void kR(const float* __restrict__ part,
    const float* __restrict__ l_ws, float* __restrict__ xwn,
    float* __restrict__ zbuf, int nchunk) {
  int js = blockIdx.x, h = blockIdx.y, b = blockIdx.z, t = threadIdx.x;
  int bid = ((b*NH + h)*4 + js);
  for (int k = t; k < 48; k += 192) zbuf[bid*48 + k] = 0.f;
  int j = js*192 + t;
  float s = 0.f;
  for (int c = 0; c < nchunk; ++c)
    s += part[((size_t)(b*nchunk + c)*NH + h)*DM + j];
  xwn[((size_t)b*NH + h)*DM + j] = s / l_ws[b*NH + h];
}

// kE1': out0acc[b, h*64+c] += sum_{j in 64-slice} xwn[b,h,j] * wvg[j, h*64+c]
__global__ __launch_bounds__(64) void kE1p(const float* __restrict__ xwn,
    const float* __restrict__ wvg, float* __restrict__ out0acc) {
  int js = blockIdx.x, h = blockIdx.y, b = blockIdx.z, t = threadIdx.x;
  __shared__ float xs[64];
  xs[t] = xwn[((size_t)b*NH + h)*DM + js*64 + t];
  __syncthreads();
  float acc = 0.f;
#pragma unroll 8
  for (int jj = 0; jj < 64; ++jj)
    acc += xs[jj] * wvg[(size_t)(js*64 + jj)*DM + h*64 + t];
  atomicAdd(&out0acc[b*DM + h*64 + t], acc);
}

// kT: 768x768 matvec, j-split (64 blocks x 12 rows), both batches, atomic accum.
// outacc[b][c] += sum_j (inraw[b][j]+bias[j]) * W[j][c]
__global__ __launch_bounds__(192) void kT(const float* __restrict__ inraw,
    const float* __restrict__ bias, const float* __restrict__ W,
    float* __restrict__ outacc) {
  int jb = blockIdx.x, t = threadIdx.x;
  const int JR = 12;
  __shared__ float xs[2][JR];
  int j0 = jb*JR;
  if (t < 2*JR) {
    int bb = t / JR, jj = t % JR;
    float v = inraw[bb*DM + j0 + jj];
    if (bias) v += bias[j0 + jj];
    xs[bb][jj] = v;
  }
  __syncthreads();
  float4 a0 = {0,0,0,0}, a1 = {0,0,0,0};
  const float4* W4 = (const float4*)W;
#pragma unroll
  for (int jj = 0; jj < JR; ++jj) {
    float4 wv = W4[(size_t)(j0 + jj)*192 + t];
    float s0 = xs[0][jj], s1 = xs[1][jj];
    a0.x += s0*wv.x; a0.y += s0*wv.y; a0.z += s0*wv.z; a0.w += s0*wv.w;
    a1.x += s1*wv.x; a1.y += s1*wv.y; a1.z += s1*wv.z; a1.w += s1*wv.w;
  }
  int c = t*4;
  atomicAdd(&outacc[c+0], a0.x); atomicAdd(&outacc[c+1], a0.y);
  atomicAdd(&outacc[c+2], a0.z); atomicAdd(&outacc[c+3], a0.w);
  atomicAdd(&outacc[DM+c+0], a1.x); atomicAdd(&outacc[DM+c+1], a1.y);
  atomicAdd(&outacc[DM+c+2], a1.z); atomicAdd(&outacc[DM+c+3], a1.w);
}

// kT3: out[b, tile*64+c] = tanh(pooledraw[b,:]+bp) . wfc[:, tile*64+c] + bfc
// 512 threads = 64 c-lanes x 8 j-groups; complete (non-atomic) write to d_out.
__global__ __launch_bounds__(512) void kT3(const float* __restrict__ pooledraw,
    const float* __restrict__ bp, const float* __restrict__ wfc,
    const float* __restrict__ bfc, float* __restrict__ out) {
  int tile = blockIdx.x, b = blockIdx.y, t = threadIdx.x;
  __shared__ float pl[DM];
  __shared__ float red[8][64];
  for (int i = t; i < DM; i += 512) pl[i] = tanhf(pooledraw[b*DM + i] + bp[i]);
  __syncthreads();
  int c = t & 63, jg = t >> 6;
  float acc = 0.f;
  for (int jj = 0; jj < 96; ++jj) {
    int j = jg*96 + jj;
    acc += pl[j] * wfc[(size_t)j*OUTC + tile*64 + c];
  }
  red[jg][c] = acc;
  __syncthreads();
  if (t < 64) {
    float r = bfc[tile*64 + t];
#pragma unroll
    for (int g = 0; g < 8; ++g) r += red[g][t];
    out[(size_t)b*OUTC + tile*64 + t] = r;
  }
}

extern "C" void kernel_launch(void* const* d_in, const int* in_sizes, int n_in,
                              void* d_out, int out_size, void* d_ws, size_t ws_size,
                              hipStream_t stream) {
  const float* x   = (const float*)d_in[0];
  const float* wqg = (const float*)d_in[7];
  const float* bqg = (const float*)d_in[8];
  const float* wkg = (const float*)d_in[9];
  const float* bkg = (const float*)d_in[10];
  const float* wvg = (const float*)d_in[11];
  const float* bvg = (const float*)d_in[12];
  const float* wo  = (const float*)d_in[13];
  const float* bo  = (const float*)d_in[14];
  const float* wp  = (const float*)d_in[15];
  const float* bp  = (const float*)d_in[16];
  const float* wfc = (const float*)d_in[17];
  const float* bfc = (const float*)d_in[18];

  float* ws        = (float*)d_ws;
  float* qpart     = ws;             // 12288
  float* qg        = ws + 12288;     // 1536
  float* qb        = ws + 13824;     // 24
  float* l         = ws + 13848;     // 24 (pad to 13872)
  float* qw        = ws + 13872;     // 18432
  float* xwn       = ws + 32304;     // 18432
  float* out0acc   = ws + 50736;     // 1536 ┐
  float* attnraw   = ws + 52272;     // 1536 │ zbuf (4608, zeroed by kR)
  float* pooledraw = ws + 53808;     // 1536 ┘
  float* part      = ws + 55360;     // up to 2*128*12*768 = 2359296

  // chunk count for kB partials, bounded by ws_size (measured ws ≈ 256 MB)
  size_t need128 = (55360 + (size_t)2*128*NH*DM) * 4;
  int nchunk = (ws_size >= need128) ? 128 : 64;

  kQ  <<<dim3(NH, BB, 8), 256, 0, stream>>>(x, wqg, qpart);
  kQf <<<dim3(NH, BB),     64, 0, stream>>>(qpart, bqg, bkg, qg, qb, l);
  kAp <<<dim3(NH, BB, 4), 192, 0, stream>>>(qg, wkg, qw);
  if (nchunk == 128)
    kB<32><<<dim3(128, BB), 256, 0, stream>>>(x, qw, qb, l, part, 128);
  else
    kB<64><<<dim3(64,  BB), 256, 0, stream>>>(x, qw, qb, l, part, 64);
  kR  <<<dim3(4, NH, BB), 192, 0, stream>>>(part, l, xwn, out0acc, nchunk);
  kE1p<<<dim3(12, NH, BB), 64, 0, stream>>>(xwn, wvg, out0acc);
  kT  <<<dim3(64),        192, 0, stream>>>(out0acc, bvg, wo, attnraw);
  kT  <<<dim3(64),        192, 0, stream>>>(attnraw,  bo, wp, pooledraw);
  kT3 <<<dim3(8, BB),     512, 0, stream>>>(pooledraw, bp, wfc, bfc, (float*)d_out);
}